// Round 1
// baseline (1263.802 us; speedup 1.0000x reference)
//
#include <hip/hip_runtime.h>
#include <math.h>

// Problem dims
#define B 64
#define S 2048
#define E 512
#define HD 512
#define TD 128

// Workspace layout (in floats)
#define OFF_MASK   0                        // B*S
#define OFF_CTXP   (OFF_MASK + B*S)         // 8*B*E  column-sum partials
#define OFF_LENP   (OFF_CTXP + 8*B*E)       // 8*B    length partials
#define OFF_CB     (OFF_LENP + 8*B)         // B*HD   per-batch attention bias
#define OFF_SC     (OFF_CB + B*HD)          // B*S    raw scores
#define OFF_SMAX   (OFF_SC + B*S)           // B
#define OFF_SDEN   (OFF_SMAX + B)           // B
#define OFF_REPP   (OFF_SDEN + B)           // 8*B*E  rep partials (no atomics -> deterministic)
#define OFF_H1     (OFF_REPP + 8*B*E)       // B*HD
#define OFF_H2     (OFF_H1 + B*HD)          // B*HD

// ---------------------------------------------------------------------------
// K1: per-(batch, 256-row chunk): row sums -> mask, column partial sums, length
// ---------------------------------------------------------------------------
__global__ __launch_bounds__(256)
void k1_maskcol(const float* __restrict__ words, float* __restrict__ mask,
                float* __restrict__ ctxp, float* __restrict__ lenp)
{
    int bid = blockIdx.x;            // 512 = B * 8
    int b = bid >> 3, ch = bid & 7;
    int t = threadIdx.x;
    int w = t >> 6, l = t & 63;
    __shared__ __align__(16) float colred[4][E];
    __shared__ float lenred[4];
    const float* base = words + (size_t)(b * S + ch * 256) * E;
    float4 c0 = make_float4(0.f,0.f,0.f,0.f), c1 = make_float4(0.f,0.f,0.f,0.f);
    float wlen = 0.0f;
    for (int r = w; r < 256; r += 4) {
        const float* row = base + (size_t)r * E;
        float4 a  = *(const float4*)(row + 4*l);        // cols 4l..4l+3
        float4 bb = *(const float4*)(row + 256 + 4*l);  // cols 256+4l..
        float rs = a.x+a.y+a.z+a.w + bb.x+bb.y+bb.z+bb.w;
        #pragma unroll
        for (int m = 1; m < 64; m <<= 1) rs += __shfl_xor(rs, m);
        c0.x += a.x;  c0.y += a.y;  c0.z += a.z;  c0.w += a.w;
        c1.x += bb.x; c1.y += bb.y; c1.z += bb.z; c1.w += bb.w;
        if (l == 0) {
            float mv = (rs != 0.0f) ? 1.0f : 0.0f;   // sign(|sum|)
            mask[(size_t)b*S + ch*256 + r] = mv;
            wlen += mv;
        }
    }
    *(float4*)&colred[w][4*l]       = c0;
    *(float4*)&colred[w][256 + 4*l] = c1;
    if (l == 0) lenred[w] = wlen;
    __syncthreads();
    float s1 = colred[0][t]+colred[1][t]+colred[2][t]+colred[3][t];
    float s2 = colred[0][t+256]+colred[1][t+256]+colred[2][t+256]+colred[3][t+256];
    size_t o = ((size_t)ch * B + b) * E;
    ctxp[o + t]       = s1;
    ctxp[o + t + 256] = s2;
    if (t == 0) lenp[ch*B + b] = lenred[0]+lenred[1]+lenred[2]+lenred[3];
}

// ---------------------------------------------------------------------------
// K2: cb[b,h] = b_att[h] + context_b . W_att[E: , h]
// ---------------------------------------------------------------------------
__global__ __launch_bounds__(256)
void k2_cb(const float* __restrict__ W_att, const float* __restrict__ b_att,
           const float* __restrict__ ctxp, const float* __restrict__ lenp,
           float* __restrict__ cb)
{
    int bid = blockIdx.x;            // 128 = B * 2
    int b = bid >> 1, hc = bid & 1;
    int t = threadIdx.x;
    __shared__ float ctxL[E];
    float len = 0.f;
    #pragma unroll
    for (int k = 0; k < 8; ++k) len += lenp[k*B + b];
    float inv = 1.0f / len;
    for (int c = t; c < E; c += 256) {
        float sv = 0.f;
        #pragma unroll
        for (int k = 0; k < 8; ++k) sv += ctxp[((size_t)k*B + b)*E + c];
        ctxL[c] = sv * inv;
    }
    __syncthreads();
    int h = hc*256 + t;
    const float* Wb = W_att + (size_t)E * HD;   // bottom half rows
    float acc = b_att[h];
    #pragma unroll 8
    for (int e = 0; e < E; ++e) acc += ctxL[e] * Wb[(size_t)e*HD + h];
    cb[(size_t)b*HD + h] = acc;
}

// ---------------------------------------------------------------------------
// K3 (dominant): scores[b,s] = sum_h tanh( words[b,s]·W_att[:E,h] + cb[b,h] )*v[h]
// 512 threads = 8 waves; tile = 32 rows; A staged transposed+swizzled in 64KB LDS.
// Each thread: 4 rows x 8 cols register tile; per e: 1 ds_read_b128 (broadcast)
// + 2 global float4 (W, L1/L2-cached) + 32 v_fma_f32.
// ---------------------------------------------------------------------------
__global__ __launch_bounds__(512, 4)
void k3_scores(const float* __restrict__ words, const float* __restrict__ W_att,
               const float* __restrict__ cb, const float* __restrict__ v,
               float* __restrict__ scores)
{
    __shared__ __align__(16) float At[E * 32];   // 64 KB: [e][r^swz]
    int bid = blockIdx.x;            // 4096 = B * 64
    int b = bid >> 6, st = bid & 63;
    int s0 = st * 32;
    int t = threadIdx.x;
    int tx = t & 63, ty = t >> 6;    // ty == wave id (rows r0=4*ty), tx -> cols
    const float* Abase = words + (size_t)(b * S + s0) * E;

    // ---- stage A^T with XOR swizzle: At[e][ r ^ ((e>>2 & 7)<<2) ] = A[r][e]
    {
        int r = t >> 4, eg = t & 15;               // 16 threads per row
        const float* rowp = Abase + (size_t)r * E;
        #pragma unroll
        for (int it = 0; it < 8; ++it) {
            int e0 = eg*4 + 64*it;
            float4 val = *(const float4*)(rowp + e0);
            float vv[4] = {val.x, val.y, val.z, val.w};
            #pragma unroll
            for (int i = 0; i < 4; ++i) {
                int e = e0 + i;
                int rs = r ^ (((e >> 2) & 7) << 2);
                At[e*32 + rs] = vv[i];
            }
        }
    }
    __syncthreads();

    float acc[4][8];
    #pragma unroll
    for (int i = 0; i < 4; ++i)
        #pragma unroll
        for (int j = 0; j < 8; ++j) acc[i][j] = 0.f;

    const float* wp0 = W_att + tx*4;         // cols tx*4..tx*4+3
    const float* wp1 = W_att + tx*4 + 256;   // cols 256+tx*4..

    #pragma unroll 2
    for (int e = 0; e < E; ++e) {
        float4 a4 = *(const float4*)&At[e*32 + ((ty ^ ((e >> 2) & 7)) << 2)];
        float4 w0 = *(const float4*)(wp0 + (size_t)e*HD);
        float4 w1 = *(const float4*)(wp1 + (size_t)e*HD);
        float aa[4]  = {a4.x, a4.y, a4.z, a4.w};
        float wa[4]  = {w0.x, w0.y, w0.z, w0.w};
        float wbv[4] = {w1.x, w1.y, w1.z, w1.w};
        #pragma unroll
        for (int i = 0; i < 4; ++i) {
            #pragma unroll
            for (int j = 0; j < 4; ++j) {
                acc[i][j]   = fmaf(aa[i], wa[j],  acc[i][j]);
                acc[i][j+4] = fmaf(aa[i], wbv[j], acc[i][j+4]);
            }
        }
    }

    // epilogue: tanh + dot with v, then wave-wide reduction over tx (all 512 cols)
    float sc[4] = {0.f, 0.f, 0.f, 0.f};
    #pragma unroll
    for (int j = 0; j < 8; ++j) {
        int col = (j < 4) ? (tx*4 + j) : (256 + tx*4 + (j - 4));
        float cbv = cb[(size_t)b*HD + col];
        float vv  = v[col];
        #pragma unroll
        for (int i = 0; i < 4; ++i)
            sc[i] += tanhf(acc[i][j] + cbv) * vv;
    }
    #pragma unroll
    for (int m = 1; m < 64; m <<= 1) {
        sc[0] += __shfl_xor(sc[0], m);
        sc[1] += __shfl_xor(sc[1], m);
        sc[2] += __shfl_xor(sc[2], m);
        sc[3] += __shfl_xor(sc[3], m);
    }
    if (tx == 0) {
        #pragma unroll
        for (int i = 0; i < 4; ++i)
            scores[(size_t)b*S + s0 + ty*4 + i] = sc[i];
    }
}

// ---------------------------------------------------------------------------
// K4a: per-batch masked max + exp-sum
// ---------------------------------------------------------------------------
__global__ __launch_bounds__(256)
void k4a_softstats(const float* __restrict__ scores, const float* __restrict__ mask,
                   float* __restrict__ smax, float* __restrict__ sden)
{
    int b = blockIdx.x, t = threadIdx.x;
    __shared__ float red[256];
    float xs[8];
    float mx = -1e30f;
    #pragma unroll
    for (int k = 0; k < 8; ++k) {
        int s = t + 256*k;
        float m = mask[(size_t)b*S + s];
        float x = (m > 0.0f) ? scores[(size_t)b*S + s] : -1e30f;
        xs[k] = x; mx = fmaxf(mx, x);
    }
    red[t] = mx; __syncthreads();
    for (int off = 128; off > 0; off >>= 1) {
        if (t < off) red[t] = fmaxf(red[t], red[t+off]);
        __syncthreads();
    }
    float gmax = red[0]; __syncthreads();
    float se = 0.f;
    #pragma unroll
    for (int k = 0; k < 8; ++k) se += expf(xs[k] - gmax);
    red[t] = se; __syncthreads();
    for (int off = 128; off > 0; off >>= 1) {
        if (t < off) red[t] += red[t+off];
        __syncthreads();
    }
    if (t == 0) { smax[b] = gmax; sden[b] = red[0]; }
}

// ---------------------------------------------------------------------------
// K4b: rep partials: repp[ch,b,e] = sum_{s in chunk} attn[b,s]*words[b,s,e]
// ---------------------------------------------------------------------------
__global__ __launch_bounds__(256)
void k4b_rep(const float* __restrict__ words, const float* __restrict__ scores,
             const float* __restrict__ mask, const float* __restrict__ smax,
             const float* __restrict__ sden, float* __restrict__ repp)
{
    int bid = blockIdx.x;            // 512 = B * 8
    int b = bid >> 3, ch = bid & 7;
    int t = threadIdx.x;
    __shared__ float wrow[256];
    int s = ch*256 + t;
    {
        float m = mask[(size_t)b*S + s];
        float x = (m > 0.0f) ? scores[(size_t)b*S + s] : -1e30f;
        wrow[t] = expf(x - smax[b]) / sden[b];   // masked rows -> exp(-huge)=0
    }
    __syncthreads();
    const float* base = words + (size_t)(b*S + ch*256)*E + 2*t;
    float2 acc = make_float2(0.f, 0.f);
    #pragma unroll 4
    for (int r = 0; r < 256; ++r) {
        float2 wv = *(const float2*)(base + (size_t)r*E);
        float a = wrow[r];
        acc.x = fmaf(a, wv.x, acc.x);
        acc.y = fmaf(a, wv.y, acc.y);
    }
    size_t o = ((size_t)ch*B + b)*E + 2*t;
    *(float2*)&repp[o] = acc;
}

// ---------------------------------------------------------------------------
// K5a: h1 = relu(rep @ W1 + b1)   (also reduces rep partials)
// ---------------------------------------------------------------------------
__global__ __launch_bounds__(256)
void k5a_l1(const float* __restrict__ repp, const float* __restrict__ W1,
            const float* __restrict__ b1, float* __restrict__ h1)
{
    int bid = blockIdx.x;            // 128 = B * 2
    int b = bid >> 1, hc = bid & 1;
    int t = threadIdx.x;
    __shared__ float repL[E];
    for (int c = t; c < E; c += 256) {
        float sv = 0.f;
        #pragma unroll
        for (int k = 0; k < 8; ++k) sv += repp[((size_t)k*B + b)*E + c];
        repL[c] = sv;
    }
    __syncthreads();
    int h = hc*256 + t;
    float acc = b1[h];
    #pragma unroll 8
    for (int e = 0; e < E; ++e) acc += repL[e] * W1[(size_t)e*HD + h];
    h1[(size_t)b*HD + h] = fmaxf(acc, 0.f);
}

// ---------------------------------------------------------------------------
// K5b: h2 = relu(h1 @ W2 + b2)
// ---------------------------------------------------------------------------
__global__ __launch_bounds__(256)
void k5b_l2(const float* __restrict__ h1, const float* __restrict__ W2,
            const float* __restrict__ b2, float* __restrict__ h2)
{
    int bid = blockIdx.x;            // 128
    int b = bid >> 1, hc = bid & 1;
    int t = threadIdx.x;
    __shared__ float inL[HD];
    for (int c = t; c < HD; c += 256) inL[c] = h1[(size_t)b*HD + c];
    __syncthreads();
    int h = hc*256 + t;
    float acc = b2[h];
    #pragma unroll 8
    for (int e = 0; e < HD; ++e) acc += inL[e] * W2[(size_t)e*HD + h];
    h2[(size_t)b*HD + h] = fmaxf(acc, 0.f);
}

// ---------------------------------------------------------------------------
// K5c: out = h2 @ W3 + b3
// ---------------------------------------------------------------------------
__global__ __launch_bounds__(128)
void k5c_l3(const float* __restrict__ h2, const float* __restrict__ W3,
            const float* __restrict__ b3, float* __restrict__ out)
{
    int b = blockIdx.x;              // 64
    int t = threadIdx.x;             // 128
    __shared__ float inL[HD];
    for (int c = t; c < HD; c += 128) inL[c] = h2[(size_t)b*HD + c];
    __syncthreads();
    float acc = b3[t];
    #pragma unroll 8
    for (int e = 0; e < HD; ++e) acc += inL[e] * W3[(size_t)e*TD + t];
    out[(size_t)b*TD + t] = acc;
}

extern "C" void kernel_launch(void* const* d_in, const int* in_sizes, int n_in,
                              void* d_out, int out_size, void* d_ws, size_t ws_size,
                              hipStream_t stream)
{
    const float* words = (const float*)d_in[0];
    const float* W_att = (const float*)d_in[1];
    const float* b_att = (const float*)d_in[2];
    const float* v     = (const float*)d_in[3];
    const float* W1    = (const float*)d_in[4];
    const float* b1    = (const float*)d_in[5];
    const float* W2    = (const float*)d_in[6];
    const float* b2    = (const float*)d_in[7];
    const float* W3    = (const float*)d_in[8];
    const float* b3    = (const float*)d_in[9];
    (void)in_sizes; (void)n_in; (void)out_size; (void)ws_size;

    float* ws   = (float*)d_ws;
    float* mask = ws + OFF_MASK;
    float* ctxp = ws + OFF_CTXP;
    float* lenp = ws + OFF_LENP;
    float* cb   = ws + OFF_CB;
    float* sc   = ws + OFF_SC;
    float* smax = ws + OFF_SMAX;
    float* sden = ws + OFF_SDEN;
    float* repp = ws + OFF_REPP;
    float* h1   = ws + OFF_H1;
    float* h2   = ws + OFF_H2;
    float* out  = (float*)d_out;

    hipLaunchKernelGGL(k1_maskcol,   dim3(B*8),  dim3(256), 0, stream, words, mask, ctxp, lenp);
    hipLaunchKernelGGL(k2_cb,        dim3(B*2),  dim3(256), 0, stream, W_att, b_att, ctxp, lenp, cb);
    hipLaunchKernelGGL(k3_scores,    dim3(B*64), dim3(512), 0, stream, words, W_att, cb, v, sc);
    hipLaunchKernelGGL(k4a_softstats,dim3(B),    dim3(256), 0, stream, sc, mask, smax, sden);
    hipLaunchKernelGGL(k4b_rep,      dim3(B*8),  dim3(256), 0, stream, words, sc, mask, smax, sden, repp);
    hipLaunchKernelGGL(k5a_l1,       dim3(B*2),  dim3(256), 0, stream, repp, W1, b1, h1);
    hipLaunchKernelGGL(k5b_l2,       dim3(B*2),  dim3(256), 0, stream, h1, W2, b2, h2);
    hipLaunchKernelGGL(k5c_l3,       dim3(B),    dim3(128), 0, stream, h2, W3, b3, out);
}

// Round 2
// 477.473 us; speedup vs baseline: 2.6469x; 2.6469x over previous
//
#include <hip/hip_runtime.h>
#include <hip/hip_bf16.h>
#include <math.h>

// Problem dims
#define B 64
#define S 2048
#define E 512
#define HD 512
#define TD 128
#define M_TOT (B*S)

// Workspace layout (in floats)
#define OFF_MASK   0                        // B*S
#define OFF_CTXP   (OFF_MASK + B*S)         // 8*B*E
#define OFF_LENP   (OFF_CTXP + 8*B*E)       // 8*B
#define OFF_CB     (OFF_LENP + 8*B)         // B*HD
#define OFF_SC     (OFF_CB + B*HD)          // B*S combined masked scores
#define OFF_SMAX   (OFF_SC + B*S)           // B
#define OFF_SDEN   (OFF_SMAX + B)           // B
#define OFF_REPP   (OFF_SDEN + B)           // 8*B*E
#define OFF_H1     (OFF_REPP + 8*B*E)       // B*HD
#define OFF_H2     (OFF_H1 + B*HD)          // B*HD
#define OFF_SCP    (OFF_H2 + B*HD)          // 2*B*S  score partials (2 N-chunks)
#define OFF_WPH    (OFF_SCP + 2*B*S)        // 262144 bf16 = 131072 floats (W hi packed)
#define OFF_WPL    (OFF_WPH + 131072)       // 131072 floats (W lo packed)

typedef __attribute__((ext_vector_type(8))) short short8;
typedef __attribute__((ext_vector_type(4))) float f32x4;

__device__ inline unsigned short f2bf(float x) {
    __hip_bfloat16 h = __float2bfloat16(x);
    unsigned short u; __builtin_memcpy(&u, &h, 2); return u;
}
__device__ inline float bf2f(unsigned short u) {
    __hip_bfloat16 h; __builtin_memcpy(&h, &u, 2); return __bfloat162float(h);
}

#define GLOAD_LDS16(gpu, lds) \
    __builtin_amdgcn_global_load_lds((__attribute__((address_space(1))) const void*)(gpu), \
                                     (__attribute__((address_space(3))) void*)(lds), 16, 0, 0)

// ---------------------------------------------------------------------------
// k0: pack top half of W_att (rows 0..E-1) into MFMA B-fragment layout, hi/lo.
// Frag layout for 16x16x32 bf16 B: lane l holds B[k=(l>>4)*8+j][col=l&15].
// Wpk[kstep][f][lane][j], kstep=e>>5, f=h>>4, lane=((e>>3)&3)*16+(h&15), j=e&7
// ---------------------------------------------------------------------------
__global__ __launch_bounds__(256)
void k0_pack(const float* __restrict__ W_att, unsigned short* __restrict__ WpkH,
             unsigned short* __restrict__ WpkL)
{
    int tid = blockIdx.x*256 + threadIdx.x;   // 262144 total
    int e = tid >> 9, h = tid & 511;
    float w = W_att[(size_t)e*HD + h];
    unsigned short hi = f2bf(w);
    unsigned short lo = f2bf(w - bf2f(hi));
    int kstep = e >> 5, kb = (e >> 3) & 3, j = e & 7, f = h >> 4, l15 = h & 15;
    size_t dst = ((((size_t)kstep*32 + f)*64) + kb*16 + l15)*8 + j;
    WpkH[dst] = hi; WpkL[dst] = lo;
}

// ---------------------------------------------------------------------------
// K1: mask, column partial sums, lengths (unchanged)
// ---------------------------------------------------------------------------
__global__ __launch_bounds__(256)
void k1_maskcol(const float* __restrict__ words, float* __restrict__ mask,
                float* __restrict__ ctxp, float* __restrict__ lenp)
{
    int bid = blockIdx.x;            // 512 = B * 8
    int b = bid >> 3, ch = bid & 7;
    int t = threadIdx.x;
    int w = t >> 6, l = t & 63;
    __shared__ __align__(16) float colred[4][E];
    __shared__ float lenred[4];
    const float* base = words + (size_t)(b * S + ch * 256) * E;
    float4 c0 = make_float4(0.f,0.f,0.f,0.f), c1 = make_float4(0.f,0.f,0.f,0.f);
    float wlen = 0.0f;
    for (int r = w; r < 256; r += 4) {
        const float* row = base + (size_t)r * E;
        float4 a  = *(const float4*)(row + 4*l);
        float4 bb = *(const float4*)(row + 256 + 4*l);
        float rs = a.x+a.y+a.z+a.w + bb.x+bb.y+bb.z+bb.w;
        #pragma unroll
        for (int m = 1; m < 64; m <<= 1) rs += __shfl_xor(rs, m);
        c0.x += a.x;  c0.y += a.y;  c0.z += a.z;  c0.w += a.w;
        c1.x += bb.x; c1.y += bb.y; c1.z += bb.z; c1.w += bb.w;
        if (l == 0) {
            float mv = (rs != 0.0f) ? 1.0f : 0.0f;
            mask[(size_t)b*S + ch*256 + r] = mv;
            wlen += mv;
        }
    }
    *(float4*)&colred[w][4*l]       = c0;
    *(float4*)&colred[w][256 + 4*l] = c1;
    if (l == 0) lenred[w] = wlen;
    __syncthreads();
    float s1 = colred[0][t]+colred[1][t]+colred[2][t]+colred[3][t];
    float s2 = colred[0][t+256]+colred[1][t+256]+colred[2][t+256]+colred[3][t+256];
    size_t o = ((size_t)ch * B + b) * E;
    ctxp[o + t]       = s1;
    ctxp[o + t + 256] = s2;
    if (t == 0) lenp[ch*B + b] = lenred[0]+lenred[1]+lenred[2]+lenred[3];
}

// ---------------------------------------------------------------------------
// K2: cb[b,h] = b_att[h] + context_b . W_att[E:, h]  (unchanged)
// ---------------------------------------------------------------------------
__global__ __launch_bounds__(256)
void k2_cb(const float* __restrict__ W_att, const float* __restrict__ b_att,
           const float* __restrict__ ctxp, const float* __restrict__ lenp,
           float* __restrict__ cb)
{
    int bid = blockIdx.x;            // 128
    int b = bid >> 1, hc = bid & 1;
    int t = threadIdx.x;
    __shared__ float ctxL[E];
    float len = 0.f;
    #pragma unroll
    for (int k = 0; k < 8; ++k) len += lenp[k*B + b];
    float inv = 1.0f / len;
    for (int c = t; c < E; c += 256) {
        float sv = 0.f;
        #pragma unroll
        for (int k = 0; k < 8; ++k) sv += ctxp[((size_t)k*B + b)*E + c];
        ctxL[c] = sv * inv;
    }
    __syncthreads();
    int h = hc*256 + t;
    const float* Wb = W_att + (size_t)E * HD;
    float acc = b_att[h];
    #pragma unroll 8
    for (int e = 0; e < E; ++e) acc += ctxL[e] * Wb[(size_t)e*HD + h];
    cb[(size_t)b*HD + h] = acc;
}

// ---------------------------------------------------------------------------
// K3: split-bf16 MFMA scores. Tile 256(M) x 256(N), BK=32, 8 waves (4x2).
// LDS 64KB: A hi/lo frag-packed (16KB+16KB) + B hi/lo frag-packed (16KB+16KB).
// scp[nc][m] = sum over this N-chunk's 256 cols of tanh(h+cb)*v.
// ---------------------------------------------------------------------------
#define A_HI 0
#define A_LO 16384
#define B_HI 32768
#define B_LO 49152

__global__ __launch_bounds__(512, 2)
void k3_scores(const float* __restrict__ words,
               const unsigned short* __restrict__ WpkH,
               const unsigned short* __restrict__ WpkL,
               const float* __restrict__ cb, const float* __restrict__ v,
               float* __restrict__ scp)
{
    __shared__ __align__(16) unsigned char smem[65536];
    int bid = blockIdx.x;             // 1024 = 512 mtiles * 2 nchunks
    int mt = bid >> 1, nc = bid & 1;
    int m0 = mt * 256;
    int b  = m0 >> 11;                // S = 2048
    int t = threadIdx.x;
    int lane = t & 63, wid = t >> 6;
    int wr = wid >> 1, wc = wid & 1;

    f32x4 acc[4][8];
    #pragma unroll
    for (int i = 0; i < 4; ++i)
        #pragma unroll
        for (int j = 0; j < 8; ++j) acc[i][j] = (f32x4)0.0f;

    // A-prefetch registers: 2 units of 8 floats
    float4 pA[2][2];
    int ru[2], kgu[2];
    #pragma unroll
    for (int uu = 0; uu < 2; ++uu) {
        int u = t + uu*512;
        ru[uu] = u >> 2; kgu[uu] = u & 3;
    }
    // prologue: load A for kstep 0
    #pragma unroll
    for (int uu = 0; uu < 2; ++uu) {
        const float* src = words + (size_t)(m0 + ru[uu])*E + kgu[uu]*8;
        pA[uu][0] = *(const float4*)src;
        pA[uu][1] = *(const float4*)(src + 4);
    }

    for (int kstep = 0; kstep < 16; ++kstep) {
        // ---- stage A: convert to hi/lo bf16, ds_write_b128 into frag-packed layout
        #pragma unroll
        for (int uu = 0; uu < 2; ++uu) {
            float xs[8] = {pA[uu][0].x, pA[uu][0].y, pA[uu][0].z, pA[uu][0].w,
                           pA[uu][1].x, pA[uu][1].y, pA[uu][1].z, pA[uu][1].w};
            unsigned int hw[4], lw[4];
            #pragma unroll
            for (int p = 0; p < 4; ++p) {
                unsigned short h0 = f2bf(xs[2*p]);
                unsigned short h1 = f2bf(xs[2*p+1]);
                unsigned short l0 = f2bf(xs[2*p]   - bf2f(h0));
                unsigned short l1 = f2bf(xs[2*p+1] - bf2f(h1));
                hw[p] = (unsigned int)h0 | ((unsigned int)h1 << 16);
                lw[p] = (unsigned int)l0 | ((unsigned int)l1 << 16);
            }
            int r = ru[uu], kg = kgu[uu];
            int off = (r >> 4)*1024 + kg*256 + (r & 15)*16;
            *(uint4*)&smem[A_HI + off] = make_uint4(hw[0], hw[1], hw[2], hw[3]);
            *(uint4*)&smem[A_LO + off] = make_uint4(lw[0], lw[1], lw[2], lw[3]);
        }
        // ---- stage B: global_load_lds from packed W (linear, 16B/lane)
        #pragma unroll
        for (int c = 0; c < 4; ++c) {
            int idx = wid*4 + c;                 // 0..31
            int fl = idx & 15;
            const unsigned short* srcv = (idx < 16) ? WpkH : WpkL;
            const unsigned short* g = srcv + (((size_t)kstep*32 + nc*16 + fl)*64 + lane)*8;
            unsigned int dst = ((idx < 16) ? B_HI : B_LO) + fl*1024;
            GLOAD_LDS16(g, &smem[dst]);
        }
        __syncthreads();

        // ---- prefetch A for next kstep (hides latency under MFMA)
        if (kstep < 15) {
            #pragma unroll
            for (int uu = 0; uu < 2; ++uu) {
                const float* src = words + (size_t)(m0 + ru[uu])*E + (kstep+1)*32 + kgu[uu]*8;
                pA[uu][0] = *(const float4*)src;
                pA[uu][1] = *(const float4*)(src + 4);
            }
        }

        // ---- compute: 96 MFMAs
        short8 ah[4], al[4];
        #pragma unroll
        for (int rf = 0; rf < 4; ++rf) {
            int rfg = wr*4 + rf;
            ah[rf] = *(const short8*)&smem[A_HI + rfg*1024 + lane*16];
            al[rf] = *(const short8*)&smem[A_LO + rfg*1024 + lane*16];
        }
        #pragma unroll
        for (int cf = 0; cf < 8; ++cf) {
            int fl = wc*8 + cf;
            short8 bh = *(const short8*)&smem[B_HI + fl*1024 + lane*16];
            short8 bl = *(const short8*)&smem[B_LO + fl*1024 + lane*16];
            #pragma unroll
            for (int rf = 0; rf < 4; ++rf) {
                acc[rf][cf] = __builtin_amdgcn_mfma_f32_16x16x32_bf16(ah[rf], bh, acc[rf][cf], 0, 0, 0);
                acc[rf][cf] = __builtin_amdgcn_mfma_f32_16x16x32_bf16(ah[rf], bl, acc[rf][cf], 0, 0, 0);
                acc[rf][cf] = __builtin_amdgcn_mfma_f32_16x16x32_bf16(al[rf], bh, acc[rf][cf], 0, 0, 0);
            }
        }
        __syncthreads();
    }

    // ---- epilogue: tanh(+cb)*v, reduce over cols
    float ssum[4][4];
    #pragma unroll
    for (int i = 0; i < 4; ++i)
        #pragma unroll
        for (int r = 0; r < 4; ++r) ssum[i][r] = 0.f;

    #pragma unroll
    for (int cf = 0; cf < 8; ++cf) {
        int col = nc*256 + (wc*8 + cf)*16 + (lane & 15);
        float cbv = cb[(size_t)b*HD + col];
        float vv  = v[col];
        #pragma unroll
        for (int rf = 0; rf < 4; ++rf)
            #pragma unroll
            for (int r = 0; r < 4; ++r)
                ssum[rf][r] += tanhf(acc[rf][cf][r] + cbv) * vv;
    }
    #pragma unroll
    for (int m = 1; m < 16; m <<= 1)
        #pragma unroll
        for (int rf = 0; rf < 4; ++rf)
            #pragma unroll
            for (int r = 0; r < 4; ++r)
                ssum[rf][r] += __shfl_xor(ssum[rf][r], m);

    float* scr = (float*)smem;   // reuse LDS (2x256 floats)
    if ((lane & 15) == 0) {
        #pragma unroll
        for (int rf = 0; rf < 4; ++rf)
            #pragma unroll
            for (int r = 0; r < 4; ++r)
                scr[wc*256 + wr*64 + rf*16 + (lane >> 4)*4 + r] = ssum[rf][r];
    }
    __syncthreads();
    if (t < 256) {
        float val = scr[t] + scr[256 + t];
        scp[(size_t)nc*M_TOT + m0 + t] = val;
    }
}

// ---------------------------------------------------------------------------
// K4a: combine partials, masked max + exp-sum, write combined masked scores
// ---------------------------------------------------------------------------
__global__ __launch_bounds__(256)
void k4a_softstats(const float* __restrict__ scp, const float* __restrict__ mask,
                   float* __restrict__ sc, float* __restrict__ smax, float* __restrict__ sden)
{
    int b = blockIdx.x, t = threadIdx.x;
    __shared__ float red[256];
    float xs[8];
    float mx = -1e30f;
    #pragma unroll
    for (int k = 0; k < 8; ++k) {
        size_t m = (size_t)b*S + t + 256*k;
        float x = scp[m] + scp[(size_t)M_TOT + m];
        float mk = mask[m];
        x = (mk > 0.0f) ? x : -1e30f;
        sc[m] = x;
        xs[k] = x; mx = fmaxf(mx, x);
    }
    red[t] = mx; __syncthreads();
    for (int off = 128; off > 0; off >>= 1) {
        if (t < off) red[t] = fmaxf(red[t], red[t+off]);
        __syncthreads();
    }
    float gmax = red[0]; __syncthreads();
    float se = 0.f;
    #pragma unroll
    for (int k = 0; k < 8; ++k) se += expf(xs[k] - gmax);
    red[t] = se; __syncthreads();
    for (int off = 128; off > 0; off >>= 1) {
        if (t < off) red[t] += red[t+off];
        __syncthreads();
    }
    if (t == 0) { smax[b] = gmax; sden[b] = red[0]; }
}

// ---------------------------------------------------------------------------
// K4b: rep partials (scores already masked/combined)
// ---------------------------------------------------------------------------
__global__ __launch_bounds__(256)
void k4b_rep(const float* __restrict__ words, const float* __restrict__ sc,
             const float* __restrict__ smax, const float* __restrict__ sden,
             float* __restrict__ repp)
{
    int bid = blockIdx.x;            // 512
    int b = bid >> 3, ch = bid & 7;
    int t = threadIdx.x;
    __shared__ float wrow[256];
    int s = ch*256 + t;
    wrow[t] = expf(sc[(size_t)b*S + s] - smax[b]) / sden[b];
    __syncthreads();
    const float* base = words + (size_t)(b*S + ch*256)*E + 2*t;
    float2 acc = make_float2(0.f, 0.f);
    #pragma unroll 4
    for (int r = 0; r < 256; ++r) {
        float2 wv = *(const float2*)(base + (size_t)r*E);
        float a = wrow[r];
        acc.x = fmaf(a, wv.x, acc.x);
        acc.y = fmaf(a, wv.y, acc.y);
    }
    size_t o = ((size_t)ch*B + b)*E + 2*t;
    *(float2*)&repp[o] = acc;
}

// ---------------------------------------------------------------------------
// K5a/b/c: MLP (unchanged)
// ---------------------------------------------------------------------------
__global__ __launch_bounds__(256)
void k5a_l1(const float* __restrict__ repp, const float* __restrict__ W1,
            const float* __restrict__ b1, float* __restrict__ h1)
{
    int bid = blockIdx.x;
    int b = bid >> 1, hc = bid & 1;
    int t = threadIdx.x;
    __shared__ float repL[E];
    for (int c = t; c < E; c += 256) {
        float sv = 0.f;
        #pragma unroll
        for (int k = 0; k < 8; ++k) sv += repp[((size_t)k*B + b)*E + c];
        repL[c] = sv;
    }
    __syncthreads();
    int h = hc*256 + t;
    float acc = b1[h];
    #pragma unroll 8
    for (int e = 0; e < E; ++e) acc += repL[e] * W1[(size_t)e*HD + h];
    h1[(size_t)b*HD + h] = fmaxf(acc, 0.f);
}

__global__ __launch_bounds__(256)
void k5b_l2(const float* __restrict__ h1, const float* __restrict__ W2,
            const float* __restrict__ b2, float* __restrict__ h2)
{
    int bid = blockIdx.x;
    int b = bid >> 1, hc = bid & 1;
    int t = threadIdx.x;
    __shared__ float inL[HD];
    for (int c = t; c < HD; c += 256) inL[c] = h1[(size_t)b*HD + c];
    __syncthreads();
    int h = hc*256 + t;
    float acc = b2[h];
    #pragma unroll 8
    for (int e = 0; e < HD; ++e) acc += inL[e] * W2[(size_t)e*HD + h];
    h2[(size_t)b*HD + h] = fmaxf(acc, 0.f);
}

__global__ __launch_bounds__(128)
void k5c_l3(const float* __restrict__ h2, const float* __restrict__ W3,
            const float* __restrict__ b3, float* __restrict__ out)
{
    int b = blockIdx.x;
    int t = threadIdx.x;
    __shared__ float inL[HD];
    for (int c = t; c < HD; c += 128) inL[c] = h2[(size_t)b*HD + c];
    __syncthreads();
    float acc = b3[t];
    #pragma unroll 8
    for (int e = 0; e < HD; ++e) acc += inL[e] * W3[(size_t)e*TD + t];
    out[(size_t)b*TD + t] = acc;
}

extern "C" void kernel_launch(void* const* d_in, const int* in_sizes, int n_in,
                              void* d_out, int out_size, void* d_ws, size_t ws_size,
                              hipStream_t stream)
{
    const float* words = (const float*)d_in[0];
    const float* W_att = (const float*)d_in[1];
    const float* b_att = (const float*)d_in[2];
    const float* v     = (const float*)d_in[3];
    const float* W1    = (const float*)d_in[4];
    const float* b1    = (const float*)d_in[5];
    const float* W2    = (const float*)d_in[6];
    const float* b2    = (const float*)d_in[7];
    const float* W3    = (const float*)d_in[8];
    const float* b3    = (const float*)d_in[9];
    (void)in_sizes; (void)n_in; (void)out_size; (void)ws_size;

    float* ws   = (float*)d_ws;
    float* mask = ws + OFF_MASK;
    float* ctxp = ws + OFF_CTXP;
    float* lenp = ws + OFF_LENP;
    float* cb   = ws + OFF_CB;
    float* sc   = ws + OFF_SC;
    float* smax = ws + OFF_SMAX;
    float* sden = ws + OFF_SDEN;
    float* repp = ws + OFF_REPP;
    float* h1   = ws + OFF_H1;
    float* h2   = ws + OFF_H2;
    float* scp  = ws + OFF_SCP;
    unsigned short* WpkH = (unsigned short*)(ws + OFF_WPH);
    unsigned short* WpkL = (unsigned short*)(ws + OFF_WPL);
    float* out  = (float*)d_out;

    hipLaunchKernelGGL(k0_pack,      dim3(1024), dim3(256), 0, stream, W_att, WpkH, WpkL);
    hipLaunchKernelGGL(k1_maskcol,   dim3(B*8),  dim3(256), 0, stream, words, mask, ctxp, lenp);
    hipLaunchKernelGGL(k2_cb,        dim3(B*2),  dim3(256), 0, stream, W_att, b_att, ctxp, lenp, cb);
    hipLaunchKernelGGL(k3_scores,    dim3(1024), dim3(512), 0, stream, words, WpkH, WpkL, cb, v, scp);
    hipLaunchKernelGGL(k4a_softstats,dim3(B),    dim3(256), 0, stream, scp, mask, sc, smax, sden);
    hipLaunchKernelGGL(k4b_rep,      dim3(B*8),  dim3(256), 0, stream, words, sc, smax, sden, repp);
    hipLaunchKernelGGL(k5a_l1,       dim3(B*2),  dim3(256), 0, stream, repp, W1, b1, h1);
    hipLaunchKernelGGL(k5b_l2,       dim3(B*2),  dim3(256), 0, stream, h1, W2, b2, h2);
    hipLaunchKernelGGL(k5c_l3,       dim3(B),    dim3(128), 0, stream, h2, W3, b3, out);
}

// Round 3
// 439.399 us; speedup vs baseline: 2.8762x; 1.0867x over previous
//
#include <hip/hip_runtime.h>
#include <hip/hip_bf16.h>
#include <math.h>

// Problem dims
#define B 64
#define S 2048
#define E 512
#define HD 512
#define TD 128
#define M_TOT (B*S)

// Workspace layout (in floats)
#define OFF_MASK   0                        // B*S
#define OFF_CTXP   (OFF_MASK + B*S)         // 8*B*E
#define OFF_LENP   (OFF_CTXP + 8*B*E)       // 8*B
#define OFF_CB     (OFF_LENP + 8*B)         // B*HD
#define OFF_SC     (OFF_CB + B*HD)          // B*S combined masked scores
#define OFF_SMAX   (OFF_SC + B*S)           // B
#define OFF_SDEN   (OFF_SMAX + B)           // B
#define OFF_REPP   (OFF_SDEN + B)           // 8*B*E
#define OFF_H1     (OFF_REPP + 8*B*E)       // B*HD
#define OFF_H2     (OFF_H1 + B*HD)          // B*HD
#define OFF_SCP    (OFF_H2 + B*HD)          // 2*B*S  score partials (2 N-chunks)
#define OFF_WPH    (OFF_SCP + 2*B*S)        // 262144 bf16 = 131072 floats (W hi packed)
#define OFF_WPL    (OFF_WPH + 131072)       // 131072 floats (W lo packed)

typedef __attribute__((ext_vector_type(8))) short short8;
typedef __attribute__((ext_vector_type(4))) float f32x4;

__device__ inline unsigned short f2bf(float x) {
    __hip_bfloat16 h = __float2bfloat16(x);
    unsigned short u; __builtin_memcpy(&u, &h, 2); return u;
}
__device__ inline float bf2f(unsigned short u) {
    __hip_bfloat16 h; __builtin_memcpy(&h, &u, 2); return __bfloat162float(h);
}

// fast tanh: exact saturation, ~1e-6 rel err, no NaN (e in (0,1])
__device__ inline float fast_tanh(float x) {
    float a = fabsf(x);
    float e = __expf(-2.0f * a);
    float r = (1.0f - e) / (1.0f + e);
    return copysignf(r, x);
}

// ---------------------------------------------------------------------------
// k0: pack top half of W_att (rows 0..E-1) into MFMA B-fragment layout, hi/lo.
// Frag layout for 16x16x32 bf16 B: lane l holds B[k=(l>>4)*8+j][col=l&15].
// Wpk[kstep][f][lane][j], kstep=e>>5, f=h>>4, lane=((e>>3)&3)*16+(h&15), j=e&7
// ---------------------------------------------------------------------------
__global__ __launch_bounds__(256)
void k0_pack(const float* __restrict__ W_att, unsigned short* __restrict__ WpkH,
             unsigned short* __restrict__ WpkL)
{
    int tid = blockIdx.x*256 + threadIdx.x;   // 262144 total
    int e = tid >> 9, h = tid & 511;
    float w = W_att[(size_t)e*HD + h];
    unsigned short hi = f2bf(w);
    unsigned short lo = f2bf(w - bf2f(hi));
    int kstep = e >> 5, kb = (e >> 3) & 3, j = e & 7, f = h >> 4, l15 = h & 15;
    size_t dst = ((((size_t)kstep*32 + f)*64) + kb*16 + l15)*8 + j;
    WpkH[dst] = hi; WpkL[dst] = lo;
}

// ---------------------------------------------------------------------------
// K1: mask, column partial sums, lengths (unchanged)
// ---------------------------------------------------------------------------
__global__ __launch_bounds__(256)
void k1_maskcol(const float* __restrict__ words, float* __restrict__ mask,
                float* __restrict__ ctxp, float* __restrict__ lenp)
{
    int bid = blockIdx.x;            // 512 = B * 8
    int b = bid >> 3, ch = bid & 7;
    int t = threadIdx.x;
    int w = t >> 6, l = t & 63;
    __shared__ __align__(16) float colred[4][E];
    __shared__ float lenred[4];
    const float* base = words + (size_t)(b * S + ch * 256) * E;
    float4 c0 = make_float4(0.f,0.f,0.f,0.f), c1 = make_float4(0.f,0.f,0.f,0.f);
    float wlen = 0.0f;
    for (int r = w; r < 256; r += 4) {
        const float* row = base + (size_t)r * E;
        float4 a  = *(const float4*)(row + 4*l);
        float4 bb = *(const float4*)(row + 256 + 4*l);
        float rs = a.x+a.y+a.z+a.w + bb.x+bb.y+bb.z+bb.w;
        #pragma unroll
        for (int m = 1; m < 64; m <<= 1) rs += __shfl_xor(rs, m);
        c0.x += a.x;  c0.y += a.y;  c0.z += a.z;  c0.w += a.w;
        c1.x += bb.x; c1.y += bb.y; c1.z += bb.z; c1.w += bb.w;
        if (l == 0) {
            float mv = (rs != 0.0f) ? 1.0f : 0.0f;
            mask[(size_t)b*S + ch*256 + r] = mv;
            wlen += mv;
        }
    }
    *(float4*)&colred[w][4*l]       = c0;
    *(float4*)&colred[w][256 + 4*l] = c1;
    if (l == 0) lenred[w] = wlen;
    __syncthreads();
    float s1 = colred[0][t]+colred[1][t]+colred[2][t]+colred[3][t];
    float s2 = colred[0][t+256]+colred[1][t+256]+colred[2][t+256]+colred[3][t+256];
    size_t o = ((size_t)ch * B + b) * E;
    ctxp[o + t]       = s1;
    ctxp[o + t + 256] = s2;
    if (t == 0) lenp[ch*B + b] = lenred[0]+lenred[1]+lenred[2]+lenred[3];
}

// ---------------------------------------------------------------------------
// K2: cb[b,h] = b_att[h] + context_b . W_att[E:, h]  (unchanged)
// ---------------------------------------------------------------------------
__global__ __launch_bounds__(256)
void k2_cb(const float* __restrict__ W_att, const float* __restrict__ b_att,
           const float* __restrict__ ctxp, const float* __restrict__ lenp,
           float* __restrict__ cb)
{
    int bid = blockIdx.x;            // 128
    int b = bid >> 1, hc = bid & 1;
    int t = threadIdx.x;
    __shared__ float ctxL[E];
    float len = 0.f;
    #pragma unroll
    for (int k = 0; k < 8; ++k) len += lenp[k*B + b];
    float inv = 1.0f / len;
    for (int c = t; c < E; c += 256) {
        float sv = 0.f;
        #pragma unroll
        for (int k = 0; k < 8; ++k) sv += ctxp[((size_t)k*B + b)*E + c];
        ctxL[c] = sv * inv;
    }
    __syncthreads();
    int h = hc*256 + t;
    const float* Wb = W_att + (size_t)E * HD;
    float acc = b_att[h];
    #pragma unroll 8
    for (int e = 0; e < E; ++e) acc += ctxL[e] * Wb[(size_t)e*HD + h];
    cb[(size_t)b*HD + h] = acc;
}

// ---------------------------------------------------------------------------
// K3: 2-term split-bf16 MFMA scores (A->bf16, W = hi+lo prepacked).
// Tile 256(M) x 256(N per nc), BK=32, 8 waves (4 wr x 2 wc), wave = 64x128.
// A: LDS double-buffered (2 x 16KB), frag-packed, single barrier per kstep.
// B: direct global->reg from fragment-packed Wpk (L2-resident), 2-frag-ahead.
// ---------------------------------------------------------------------------
__global__ __launch_bounds__(512, 2)
void k3_scores(const float* __restrict__ words,
               const unsigned short* __restrict__ WpkH,
               const unsigned short* __restrict__ WpkL,
               const float* __restrict__ cb, const float* __restrict__ v,
               float* __restrict__ scp)
{
    __shared__ __align__(16) unsigned char smem[32768];   // A dbuf: 2 x 16KB
    int bid = blockIdx.x;             // 1024 = 512 mtiles * 2 nchunks
    int mt = bid >> 1, nc = bid & 1;
    int m0 = mt * 256;
    int b  = m0 >> 11;                // S = 2048
    int t = threadIdx.x;
    int lane = t & 63, wid = t >> 6;
    int wr = wid >> 2, wc = wid & 3;  // placeholder (re-set below)
    wr = wid >> 1; wc = wid & 1;      // 4 row-groups x 2 col-groups

    f32x4 acc[4][8];
    #pragma unroll
    for (int i = 0; i < 4; ++i)
        #pragma unroll
        for (int j = 0; j < 8; ++j) acc[i][j] = (f32x4)0.0f;

    // ---- A staging assignment: thread t -> row r = t>>1, k-half kh = t&1 (16 elems)
    int r = t >> 1, kh = t & 1;
    const float* aSrc = words + (size_t)(m0 + r)*E + kh*16;
    int abase = (r >> 4)*1024 + (r & 15)*16;   // + kb*256
    int kb0 = kh*2;

    float4 pA[4];
    // ---- B fragment base: frag index fl = nc*16 + wc*8 + cf
    const unsigned short* bBaseH = WpkH + (((size_t)(nc*16 + wc*8))*64 + lane)*8;
    const unsigned short* bBaseL = WpkL + (((size_t)(nc*16 + wc*8))*64 + lane)*8;
    // per (kstep, cf) offset in shorts: (kstep*32 + cf) * 512

#define LOADA(ks) do { \
        const float* _s = aSrc + (ks)*32; \
        pA[0] = *(const float4*)(_s); pA[1] = *(const float4*)(_s+4); \
        pA[2] = *(const float4*)(_s+8); pA[3] = *(const float4*)(_s+12); } while(0)

#define STAGEA(buf) do { \
        float xs[16] = {pA[0].x,pA[0].y,pA[0].z,pA[0].w, pA[1].x,pA[1].y,pA[1].z,pA[1].w, \
                        pA[2].x,pA[2].y,pA[2].z,pA[2].w, pA[3].x,pA[3].y,pA[3].z,pA[3].w}; \
        unsigned int uw[8]; \
        _Pragma("unroll") \
        for (int p = 0; p < 8; ++p) \
            uw[p] = (unsigned int)f2bf(xs[2*p]) | ((unsigned int)f2bf(xs[2*p+1]) << 16); \
        *(uint4*)&(buf)[abase + kb0*256]     = make_uint4(uw[0],uw[1],uw[2],uw[3]); \
        *(uint4*)&(buf)[abase + (kb0+1)*256] = make_uint4(uw[4],uw[5],uw[6],uw[7]); } while(0)

#define LDBH(ks,cf) (*(const short8*)(bBaseH + ((size_t)(ks)*32 + (cf))*512))
#define LDBL(ks,cf) (*(const short8*)(bBaseL + ((size_t)(ks)*32 + (cf))*512))

    // ---- prologue
    LOADA(0);
    STAGEA(smem);            // buf0 <- kstep 0
    LOADA(1);                // pA <- kstep 1
    short8 bh0 = LDBH(0,0), bl0 = LDBL(0,0);
    short8 bh1 = LDBH(0,1), bl1 = LDBL(0,1);
    __syncthreads();

    for (int k = 0; k < 16; ++k) {
        unsigned char* bufc = smem + (k & 1)*16384;
        unsigned char* bufn = smem + ((k & 1) ^ 1)*16384;

        // A fragments for this kstep (conflict-free b128 reads)
        short8 ah[4];
        #pragma unroll
        for (int rf = 0; rf < 4; ++rf)
            ah[rf] = *(const short8*)&bufc[(wr*4 + rf)*1024 + lane*16];

        // stage next A tile, refill pA
        if (k < 15) STAGEA(bufn);
        if (k < 14) LOADA(k + 2);

        int kn = (k < 15) ? (k + 1) : 15;   // clamp (redundant load on last iter)
        #pragma unroll
        for (int cf = 0; cf < 8; ++cf) {
            short8 ch = (cf & 1) ? bh1 : bh0;
            short8 cl = (cf & 1) ? bl1 : bl0;
            // issue 2-ahead loads (cross into next kstep at cf=6,7)
            if (cf < 6) {
                if (cf & 1) { bh1 = LDBH(k, cf+2); bl1 = LDBL(k, cf+2); }
                else        { bh0 = LDBH(k, cf+2); bl0 = LDBL(k, cf+2); }
            } else {
                if (cf & 1) { bh1 = LDBH(kn, 1); bl1 = LDBL(kn, 1); }
                else        { bh0 = LDBH(kn, 0); bl0 = LDBL(kn, 0); }
            }
            #pragma unroll
            for (int rf = 0; rf < 4; ++rf) {
                acc[rf][cf] = __builtin_amdgcn_mfma_f32_16x16x32_bf16(ah[rf], ch, acc[rf][cf], 0, 0, 0);
                acc[rf][cf] = __builtin_amdgcn_mfma_f32_16x16x32_bf16(ah[rf], cl, acc[rf][cf], 0, 0, 0);
            }
        }
        __syncthreads();
    }

    // ---- epilogue: tanh(+cb)*v, reduce over cols
    float ssum[4][4];
    #pragma unroll
    for (int i = 0; i < 4; ++i)
        #pragma unroll
        for (int rr = 0; rr < 4; ++rr) ssum[i][rr] = 0.f;

    #pragma unroll
    for (int cf = 0; cf < 8; ++cf) {
        int col = nc*256 + wc*128 + cf*16 + (lane & 15);
        float cbv = cb[(size_t)b*HD + col];
        float vv  = v[col];
        #pragma unroll
        for (int rf = 0; rf < 4; ++rf)
            #pragma unroll
            for (int rr = 0; rr < 4; ++rr)
                ssum[rf][rr] += fast_tanh(acc[rf][cf][rr] + cbv) * vv;
    }
    #pragma unroll
    for (int m = 1; m < 16; m <<= 1)
        #pragma unroll
        for (int rf = 0; rf < 4; ++rf)
            #pragma unroll
            for (int rr = 0; rr < 4; ++rr)
                ssum[rf][rr] += __shfl_xor(ssum[rf][rr], m);

    float* scr = (float*)smem;   // reuse LDS (2 x 256 floats); last barrier was in loop
    if ((lane & 15) == 0) {
        #pragma unroll
        for (int rf = 0; rf < 4; ++rf)
            #pragma unroll
            for (int rr = 0; rr < 4; ++rr)
                scr[wc*256 + wr*64 + rf*16 + (lane >> 4)*4 + rr] = ssum[rf][rr];
    }
    __syncthreads();
    if (t < 256) {
        float val = scr[t] + scr[256 + t];
        scp[(size_t)nc*M_TOT + m0 + t] = val;
    }
#undef LOADA
#undef STAGEA
#undef LDBH
#undef LDBL
}

// ---------------------------------------------------------------------------
// K4a: combine partials, masked max + exp-sum, write combined masked scores
// ---------------------------------------------------------------------------
__global__ __launch_bounds__(256)
void k4a_softstats(const float* __restrict__ scp, const float* __restrict__ mask,
                   float* __restrict__ sc, float* __restrict__ smax, float* __restrict__ sden)
{
    int b = blockIdx.x, t = threadIdx.x;
    __shared__ float red[256];
    float xs[8];
    float mx = -1e30f;
    #pragma unroll
    for (int k = 0; k < 8; ++k) {
        size_t m = (size_t)b*S + t + 256*k;
        float x = scp[m] + scp[(size_t)M_TOT + m];
        float mk = mask[m];
        x = (mk > 0.0f) ? x : -1e30f;
        sc[m] = x;
        xs[k] = x; mx = fmaxf(mx, x);
    }
    red[t] = mx; __syncthreads();
    for (int off = 128; off > 0; off >>= 1) {
        if (t < off) red[t] = fmaxf(red[t], red[t+off]);
        __syncthreads();
    }
    float gmax = red[0]; __syncthreads();
    float se = 0.f;
    #pragma unroll
    for (int k = 0; k < 8; ++k) se += expf(xs[k] - gmax);
    red[t] = se; __syncthreads();
    for (int off = 128; off > 0; off >>= 1) {
        if (t < off) red[t] += red[t+off];
        __syncthreads();
    }
    if (t == 0) { smax[b] = gmax; sden[b] = red[0]; }
}

// ---------------------------------------------------------------------------
// K4b: rep partials (scores already masked/combined)
// ---------------------------------------------------------------------------
__global__ __launch_bounds__(256)
void k4b_rep(const float* __restrict__ words, const float* __restrict__ sc,
             const float* __restrict__ smax, const float* __restrict__ sden,
             float* __restrict__ repp)
{
    int bid = blockIdx.x;            // 512
    int b = bid >> 3, ch = bid & 7;
    int t = threadIdx.x;
    __shared__ float wrow[256];
    int s = ch*256 + t;
    wrow[t] = expf(sc[(size_t)b*S + s] - smax[b]) / sden[b];
    __syncthreads();
    const float* base = words + (size_t)(b*S + ch*256)*E + 2*t;
    float2 acc = make_float2(0.f, 0.f);
    #pragma unroll 4
    for (int r = 0; r < 256; ++r) {
        float2 wv = *(const float2*)(base + (size_t)r*E);
        float a = wrow[r];
        acc.x = fmaf(a, wv.x, acc.x);
        acc.y = fmaf(a, wv.y, acc.y);
    }
    size_t o = ((size_t)ch*B + b)*E + 2*t;
    *(float2*)&repp[o] = acc;
}

// ---------------------------------------------------------------------------
// K5a/b/c: MLP (unchanged)
// ---------------------------------------------------------------------------
__global__ __launch_bounds__(256)
void k5a_l1(const float* __restrict__ repp, const float* __restrict__ W1,
            const float* __restrict__ b1, float* __restrict__ h1)
{
    int bid = blockIdx.x;
    int b = bid >> 1, hc = bid & 1;
    int t = threadIdx.x;
    __shared__ float repL[E];
    for (int c = t; c < E; c += 256) {
        float sv = 0.f;
        #pragma unroll
        for (int k = 0; k < 8; ++k) sv += repp[((size_t)k*B + b)*E + c];
        repL[c] = sv;
    }
    __syncthreads();
    int h = hc*256 + t;
    float acc = b1[h];
    #pragma unroll 8
    for (int e = 0; e < E; ++e) acc += repL[e] * W1[(size_t)e*HD + h];
    h1[(size_t)b*HD + h] = fmaxf(acc, 0.f);
}

__global__ __launch_bounds__(256)
void k5b_l2(const float* __restrict__ h1, const float* __restrict__ W2,
            const float* __restrict__ b2, float* __restrict__ h2)
{
    int bid = blockIdx.x;
    int b = bid >> 1, hc = bid & 1;
    int t = threadIdx.x;
    __shared__ float inL[HD];
    for (int c = t; c < HD; c += 256) inL[c] = h1[(size_t)b*HD + c];
    __syncthreads();
    int h = hc*256 + t;
    float acc = b2[h];
    #pragma unroll 8
    for (int e = 0; e < HD; ++e) acc += inL[e] * W2[(size_t)e*HD + h];
    h2[(size_t)b*HD + h] = fmaxf(acc, 0.f);
}

__global__ __launch_bounds__(128)
void k5c_l3(const float* __restrict__ h2, const float* __restrict__ W3,
            const float* __restrict__ b3, float* __restrict__ out)
{
    int b = blockIdx.x;
    int t = threadIdx.x;
    __shared__ float inL[HD];
    for (int c = t; c < HD; c += 128) inL[c] = h2[(size_t)b*HD + c];
    __syncthreads();
    float acc = b3[t];
    #pragma unroll 8
    for (int e = 0; e < HD; ++e) acc += inL[e] * W3[(size_t)e*TD + t];
    out[(size_t)b*TD + t] = acc;
}

extern "C" void kernel_launch(void* const* d_in, const int* in_sizes, int n_in,
                              void* d_out, int out_size, void* d_ws, size_t ws_size,
                              hipStream_t stream)
{
    const float* words = (const float*)d_in[0];
    const float* W_att = (const float*)d_in[1];
    const float* b_att = (const float*)d_in[2];
    const float* v     = (const float*)d_in[3];
    const float* W1    = (const float*)d_in[4];
    const float* b1    = (const float*)d_in[5];
    const float* W2    = (const float*)d_in[6];
    const float* b2    = (const float*)d_in[7];
    const float* W3    = (const float*)d_in[8];
    const float* b3    = (const float*)d_in[9];
    (void)in_sizes; (void)n_in; (void)out_size; (void)ws_size;

    float* ws   = (float*)d_ws;
    float* mask = ws + OFF_MASK;
    float* ctxp = ws + OFF_CTXP;
    float* lenp = ws + OFF_LENP;
    float* cb   = ws + OFF_CB;
    float* sc   = ws + OFF_SC;
    float* smax = ws + OFF_SMAX;
    float* sden = ws + OFF_SDEN;
    float* repp = ws + OFF_REPP;
    float* h1   = ws + OFF_H1;
    float* h2   = ws + OFF_H2;
    float* scp  = ws + OFF_SCP;
    unsigned short* WpkH = (unsigned short*)(ws + OFF_WPH);
    unsigned short* WpkL = (unsigned short*)(ws + OFF_WPL);
    float* out  = (float*)d_out;

    hipLaunchKernelGGL(k0_pack,      dim3(1024), dim3(256), 0, stream, W_att, WpkH, WpkL);
    hipLaunchKernelGGL(k1_maskcol,   dim3(B*8),  dim3(256), 0, stream, words, mask, ctxp, lenp);
    hipLaunchKernelGGL(k2_cb,        dim3(B*2),  dim3(256), 0, stream, W_att, b_att, ctxp, lenp, cb);
    hipLaunchKernelGGL(k3_scores,    dim3(1024), dim3(512), 0, stream, words, WpkH, WpkL, cb, v, scp);
    hipLaunchKernelGGL(k4a_softstats,dim3(B),    dim3(256), 0, stream, scp, mask, sc, smax, sden);
    hipLaunchKernelGGL(k4b_rep,      dim3(B*8),  dim3(256), 0, stream, words, sc, smax, sden, repp);
    hipLaunchKernelGGL(k5a_l1,       dim3(B*2),  dim3(256), 0, stream, repp, W1, b1, h1);
    hipLaunchKernelGGL(k5b_l2,       dim3(B*2),  dim3(256), 0, stream, h1, W2, b2, h2);
    hipLaunchKernelGGL(k5c_l3,       dim3(B),    dim3(128), 0, stream, h2, W3, b3, out);
}

// Round 4
// 288.657 us; speedup vs baseline: 4.3782x; 1.5222x over previous
//
#include <hip/hip_runtime.h>
#include <hip/hip_bf16.h>
#include <hip/hip_fp16.h>
#include <math.h>

// Problem dims
#define B 64
#define S 2048
#define E 512
#define HD 512
#define TD 128
#define M_TOT (B*S)

// Workspace layout (in floats)
#define OFF_MASK   0                        // B*S
#define OFF_CTXP   (OFF_MASK + B*S)         // 8*B*E
#define OFF_LENP   (OFF_CTXP + 8*B*E)       // 8*B
#define OFF_CB     (OFF_LENP + 8*B)         // B*HD
#define OFF_SC     (OFF_CB + B*HD)          // B*S combined masked scores
#define OFF_SMAX   (OFF_SC + B*S)           // B
#define OFF_SDEN   (OFF_SMAX + B)           // B
#define OFF_REPP   (OFF_SDEN + B)           // 8*B*E
#define OFF_H1     (OFF_REPP + 8*B*E)       // B*HD
#define OFF_H2     (OFF_H1 + B*HD)          // B*HD
#define OFF_SCP    (OFF_H2 + B*HD)          // 2*B*S  score partials (2 N-chunks)
#define OFF_WPK    (OFF_SCP + 2*B*S)        // 262144 fp16 = 131072 floats (W packed)

typedef __attribute__((ext_vector_type(8))) short short8;
typedef __attribute__((ext_vector_type(4))) float f32x4;

__device__ inline unsigned int f2hu(float x) {
    __half h = __float2half(x);
    unsigned short u; __builtin_memcpy(&u, &h, 2); return (unsigned int)u;
}

// fast tanh: exact saturation, ~1e-6 rel err, no NaN (e in (0,1])
__device__ inline float fast_tanh(float x) {
    float a = fabsf(x);
    float e = __expf(-2.0f * a);
    float r = (1.0f - e) / (1.0f + e);
    return copysignf(r, x);
}

// ---------------------------------------------------------------------------
// k0: pack top half of W_att (rows 0..E-1) into MFMA B-fragment layout, fp16.
// Frag layout for 16x16x32 f16 B: lane l holds B[k=(l>>4)*8+j][col=l&15].
// dst frag index fl = h>>4 (32 per kstep), lane = ((e>>3)&3)*16 + (h&15), j = e&7
// ---------------------------------------------------------------------------
__global__ __launch_bounds__(256)
void k0_pack(const float* __restrict__ W_att, unsigned short* __restrict__ Wpk)
{
    int tid = blockIdx.x*256 + threadIdx.x;   // 262144 total
    int e = tid >> 9, h = tid & 511;
    float w = W_att[(size_t)e*HD + h];
    int kstep = e >> 5, kb = (e >> 3) & 3, j = e & 7, f = h >> 4, l15 = h & 15;
    size_t dst = ((((size_t)kstep*32 + f)*64) + kb*16 + l15)*8 + j;
    Wpk[dst] = (unsigned short)f2hu(w);
}

// ---------------------------------------------------------------------------
// K1: mask, column partial sums, lengths
// ---------------------------------------------------------------------------
__global__ __launch_bounds__(256)
void k1_maskcol(const float* __restrict__ words, float* __restrict__ mask,
                float* __restrict__ ctxp, float* __restrict__ lenp)
{
    int bid = blockIdx.x;            // 512 = B * 8
    int b = bid >> 3, ch = bid & 7;
    int t = threadIdx.x;
    int w = t >> 6, l = t & 63;
    __shared__ __align__(16) float colred[4][E];
    __shared__ float lenred[4];
    const float* base = words + (size_t)(b * S + ch * 256) * E;
    float4 c0 = make_float4(0.f,0.f,0.f,0.f), c1 = make_float4(0.f,0.f,0.f,0.f);
    float wlen = 0.0f;
    for (int r = w; r < 256; r += 4) {
        const float* row = base + (size_t)r * E;
        float4 a  = *(const float4*)(row + 4*l);
        float4 bb = *(const float4*)(row + 256 + 4*l);
        float rs = a.x+a.y+a.z+a.w + bb.x+bb.y+bb.z+bb.w;
        #pragma unroll
        for (int m = 1; m < 64; m <<= 1) rs += __shfl_xor(rs, m);
        c0.x += a.x;  c0.y += a.y;  c0.z += a.z;  c0.w += a.w;
        c1.x += bb.x; c1.y += bb.y; c1.z += bb.z; c1.w += bb.w;
        if (l == 0) {
            float mv = (rs != 0.0f) ? 1.0f : 0.0f;
            mask[(size_t)b*S + ch*256 + r] = mv;
            wlen += mv;
        }
    }
    *(float4*)&colred[w][4*l]       = c0;
    *(float4*)&colred[w][256 + 4*l] = c1;
    if (l == 0) lenred[w] = wlen;
    __syncthreads();
    float s1 = colred[0][t]+colred[1][t]+colred[2][t]+colred[3][t];
    float s2 = colred[0][t+256]+colred[1][t+256]+colred[2][t+256]+colred[3][t+256];
    size_t o = ((size_t)ch * B + b) * E;
    ctxp[o + t]       = s1;
    ctxp[o + t + 256] = s2;
    if (t == 0) lenp[ch*B + b] = lenred[0]+lenred[1]+lenred[2]+lenred[3];
}

// ---------------------------------------------------------------------------
// K2: cb[b,h] = b_att[h] + context_b . W_att[E:, h]
// ---------------------------------------------------------------------------
__global__ __launch_bounds__(256)
void k2_cb(const float* __restrict__ W_att, const float* __restrict__ b_att,
           const float* __restrict__ ctxp, const float* __restrict__ lenp,
           float* __restrict__ cb)
{
    int bid = blockIdx.x;            // 128
    int b = bid >> 1, hc = bid & 1;
    int t = threadIdx.x;
    __shared__ float ctxL[E];
    float len = 0.f;
    #pragma unroll
    for (int k = 0; k < 8; ++k) len += lenp[k*B + b];
    float inv = 1.0f / len;
    for (int c = t; c < E; c += 256) {
        float sv = 0.f;
        #pragma unroll
        for (int k = 0; k < 8; ++k) sv += ctxp[((size_t)k*B + b)*E + c];
        ctxL[c] = sv * inv;
    }
    __syncthreads();
    int h = hc*256 + t;
    const float* Wb = W_att + (size_t)E * HD;
    float a0 = b_att[h], a1 = 0.f, a2 = 0.f, a3 = 0.f;
    #pragma unroll 4
    for (int e = 0; e < E; e += 4) {
        a0 += ctxL[e]   * Wb[(size_t)e*HD + h];
        a1 += ctxL[e+1] * Wb[(size_t)(e+1)*HD + h];
        a2 += ctxL[e+2] * Wb[(size_t)(e+2)*HD + h];
        a3 += ctxL[e+3] * Wb[(size_t)(e+3)*HD + h];
    }
    cb[(size_t)b*HD + h] = (a0 + a1) + (a2 + a3);
}

// ---------------------------------------------------------------------------
// K3: fp16 MFMA scores. Block tile 128(M) x 256(N per nc), BK=32, 8 waves
// (2 wr x 4 wc), wave = 64x64 => acc 64 regs. Target 2 blocks/CU.
// A: LDS double-buffered (2 x 8KB), frag-packed fp16, 1 barrier/kstep.
// B: direct global->reg from packed Wpk (L2-resident), reload frag right
//    after its last MFMA use -> one-kstep latency hiding with 16 regs.
// ---------------------------------------------------------------------------
__global__ __launch_bounds__(512, 4)
void k3_scores(const float* __restrict__ words,
               const unsigned short* __restrict__ Wpk,
               const float* __restrict__ cb, const float* __restrict__ v,
               float* __restrict__ scp)
{
    __shared__ __align__(16) unsigned char smem[16384];   // A dbuf: 2 x 8KB
    int bid = blockIdx.x;             // 2048 = 1024 mtiles * 2 nchunks
    int mt = bid >> 1, nc = bid & 1;
    int m0 = mt * 128;
    int b  = m0 >> 11;                // S = 2048
    int t = threadIdx.x;
    int lane = t & 63, wid = t >> 6;
    int wr = wid >> 2, wc = wid & 3;  // 2 row-groups x 4 col-groups

    f32x4 acc[4][4];
    #pragma unroll
    for (int i = 0; i < 4; ++i)
        #pragma unroll
        for (int j = 0; j < 4; ++j) acc[i][j] = (f32x4)0.0f;

    // ---- A staging: thread t -> row r = t>>2 (4 threads/row), k-quarter kq = t&3
    int r = t >> 2, kq = t & 3;
    const float* aSrc = words + (size_t)(m0 + r)*E + kq*8;
    int abase = (r >> 4)*1024 + kq*256 + (r & 15)*16;

    float4 pA[2];
    // ---- B fragment base: frag fl = nc*16 + wc*4 + cf
    const unsigned short* bBase = Wpk + (((size_t)(nc*16 + wc*4))*64 + lane)*8;

#define LOADA(ks) do { \
        const float* _s = aSrc + (ks)*32; \
        pA[0] = *(const float4*)(_s); pA[1] = *(const float4*)(_s+4); } while(0)

#define STAGEA(buf) do { \
        float xs[8] = {pA[0].x,pA[0].y,pA[0].z,pA[0].w, pA[1].x,pA[1].y,pA[1].z,pA[1].w}; \
        unsigned int uw[4]; \
        _Pragma("unroll") \
        for (int p = 0; p < 4; ++p) \
            uw[p] = f2hu(xs[2*p]) | (f2hu(xs[2*p+1]) << 16); \
        *(uint4*)&(buf)[abase] = make_uint4(uw[0],uw[1],uw[2],uw[3]); } while(0)

#define LDB(ks,cf) (*(const short8*)(bBase + ((size_t)(ks)*32 + (cf))*512))

    // ---- prologue
    LOADA(0);
    STAGEA(smem);            // buf0 <- kstep 0
    LOADA(1);                // pA <- kstep 1
    short8 bcur[4];
    #pragma unroll
    for (int cf = 0; cf < 4; ++cf) bcur[cf] = LDB(0, cf);
    __syncthreads();

    for (int k = 0; k < 16; ++k) {
        unsigned char* bufc = smem + (k & 1)*8192;
        unsigned char* bufn = smem + ((k & 1) ^ 1)*8192;

        // A fragments for this kstep (conflict-free b128 reads: lane*16)
        short8 ah[4];
        #pragma unroll
        for (int rf = 0; rf < 4; ++rf)
            ah[rf] = *(const short8*)&bufc[(wr*4 + rf)*1024 + lane*16];

        // stage next A tile, refill pA
        if (k < 15) STAGEA(bufn);
        if (k < 14) LOADA(k + 2);

        #pragma unroll
        for (int cf = 0; cf < 4; ++cf) {
            #pragma unroll
            for (int rf = 0; rf < 4; ++rf)
                acc[rf][cf] = __builtin_amdgcn_mfma_f32_16x16x32_f16(ah[rf], bcur[cf], acc[rf][cf], 0, 0, 0);
            // reload this frag for next kstep right after last use -> ~full
            // kstep of latency hiding with only 16 B-regs live
            if (k < 15) bcur[cf] = LDB(k + 1, cf);
        }
        __syncthreads();
    }

    // ---- epilogue: tanh(+cb)*v, reduce over cols
    float ssum[4][4];
    #pragma unroll
    for (int i = 0; i < 4; ++i)
        #pragma unroll
        for (int rr = 0; rr < 4; ++rr) ssum[i][rr] = 0.f;

    #pragma unroll
    for (int cf = 0; cf < 4; ++cf) {
        int col = nc*256 + wc*64 + cf*16 + (lane & 15);
        float cbv = cb[(size_t)b*HD + col];
        float vv  = v[col];
        #pragma unroll
        for (int rf = 0; rf < 4; ++rf)
            #pragma unroll
            for (int rr = 0; rr < 4; ++rr)
                ssum[rf][rr] += fast_tanh(acc[rf][cf][rr] + cbv) * vv;
    }
    #pragma unroll
    for (int m = 1; m < 16; m <<= 1)
        #pragma unroll
        for (int rf = 0; rf < 4; ++rf)
            #pragma unroll
            for (int rr = 0; rr < 4; ++rr)
                ssum[rf][rr] += __shfl_xor(ssum[rf][rr], m);

    float* scr = (float*)smem;   // reuse LDS (4 wc x 128 rows); loop ended w/ barrier
    if ((lane & 15) == 0) {
        #pragma unroll
        for (int rf = 0; rf < 4; ++rf)
            #pragma unroll
            for (int rr = 0; rr < 4; ++rr)
                scr[wc*128 + wr*64 + rf*16 + (lane >> 4)*4 + rr] = ssum[rf][rr];
    }
    __syncthreads();
    if (t < 128) {
        float val = (scr[t] + scr[128 + t]) + (scr[256 + t] + scr[384 + t]);
        scp[(size_t)nc*M_TOT + m0 + t] = val;
    }
#undef LOADA
#undef STAGEA
#undef LDB
}

// ---------------------------------------------------------------------------
// K4a: combine partials, masked max + exp-sum, write combined masked scores
// ---------------------------------------------------------------------------
__global__ __launch_bounds__(256)
void k4a_softstats(const float* __restrict__ scp, const float* __restrict__ mask,
                   float* __restrict__ sc, float* __restrict__ smax, float* __restrict__ sden)
{
    int b = blockIdx.x, t = threadIdx.x;
    __shared__ float red[256];
    float xs[8];
    float mx = -1e30f;
    #pragma unroll
    for (int k = 0; k < 8; ++k) {
        size_t m = (size_t)b*S + t + 256*k;
        float x = scp[m] + scp[(size_t)M_TOT + m];
        float mk = mask[m];
        x = (mk > 0.0f) ? x : -1e30f;
        sc[m] = x;
        xs[k] = x; mx = fmaxf(mx, x);
    }
    red[t] = mx; __syncthreads();
    for (int off = 128; off > 0; off >>= 1) {
        if (t < off) red[t] = fmaxf(red[t], red[t+off]);
        __syncthreads();
    }
    float gmax = red[0]; __syncthreads();
    float se = 0.f;
    #pragma unroll
    for (int k = 0; k < 8; ++k) se += expf(xs[k] - gmax);
    red[t] = se; __syncthreads();
    for (int off = 128; off > 0; off >>= 1) {
        if (t < off) red[t] += red[t+off];
        __syncthreads();
    }
    if (t == 0) { smax[b] = gmax; sden[b] = red[0]; }
}

// ---------------------------------------------------------------------------
// K4b: rep partials
// ---------------------------------------------------------------------------
__global__ __launch_bounds__(256)
void k4b_rep(const float* __restrict__ words, const float* __restrict__ sc,
             const float* __restrict__ smax, const float* __restrict__ sden,
             float* __restrict__ repp)
{
    int bid = blockIdx.x;            // 512
    int b = bid >> 3, ch = bid & 7;
    int t = threadIdx.x;
    __shared__ float wrow[256];
    int s = ch*256 + t;
    wrow[t] = expf(sc[(size_t)b*S + s] - smax[b]) / sden[b];
    __syncthreads();
    const float* base = words + (size_t)(b*S + ch*256)*E + 2*t;
    float2 acc = make_float2(0.f, 0.f);
    #pragma unroll 4
    for (int r = 0; r < 256; ++r) {
        float2 wv = *(const float2*)(base + (size_t)r*E);
        float a = wrow[r];
        acc.x = fmaf(a, wv.x, acc.x);
        acc.y = fmaf(a, wv.y, acc.y);
    }
    size_t o = ((size_t)ch*B + b)*E + 2*t;
    *(float2*)&repp[o] = acc;
}

// ---------------------------------------------------------------------------
// K5a/b/c: MLP
// ---------------------------------------------------------------------------
__global__ __launch_bounds__(256)
void k5a_l1(const float* __restrict__ repp, const float* __restrict__ W1,
            const float* __restrict__ b1, float* __restrict__ h1)
{
    int bid = blockIdx.x;
    int b = bid >> 1, hc = bid & 1;
    int t = threadIdx.x;
    __shared__ float repL[E];
    for (int c = t; c < E; c += 256) {
        float sv = 0.f;
        #pragma unroll
        for (int k = 0; k < 8; ++k) sv += repp[((size_t)k*B + b)*E + c];
        repL[c] = sv;
    }
    __syncthreads();
    int h = hc*256 + t;
    float a0 = b1[h], a1 = 0.f, a2 = 0.f, a3 = 0.f;
    #pragma unroll 4
    for (int e = 0; e < E; e += 4) {
        a0 += repL[e]   * W1[(size_t)e*HD + h];
        a1 += repL[e+1] * W1[(size_t)(e+1)*HD + h];
        a2 += repL[e+2] * W1[(size_t)(e+2)*HD + h];
        a3 += repL[e+3] * W1[(size_t)(e+3)*HD + h];
    }
    h1[(size_t)b*HD + h] = fmaxf((a0 + a1) + (a2 + a3), 0.f);
}

__global__ __launch_bounds__(256)
void k5b_l2(const float* __restrict__ h1, const float* __restrict__ W2,
            const float* __restrict__ b2, float* __restrict__ h2)
{
    int bid = blockIdx.x;
    int b = bid >> 1, hc = bid & 1;
    int t = threadIdx.x;
    __shared__ float inL[HD];
    for (int c = t; c < HD; c += 256) inL[c] = h1[(size_t)b*HD + c];
    __syncthreads();
    int h = hc*256 + t;
    float a0 = b2[h], a1 = 0.f, a2 = 0.f, a3 = 0.f;
    #pragma unroll 4
    for (int e = 0; e < HD; e += 4) {
        a0 += inL[e]   * W2[(size_t)e*HD + h];
        a1 += inL[e+1] * W2[(size_t)(e+1)*HD + h];
        a2 += inL[e+2] * W2[(size_t)(e+2)*HD + h];
        a3 += inL[e+3] * W2[(size_t)(e+3)*HD + h];
    }
    h2[(size_t)b*HD + h] = fmaxf((a0 + a1) + (a2 + a3), 0.f);
}

__global__ __launch_bounds__(128)
void k5c_l3(const float* __restrict__ h2, const float* __restrict__ W3,
            const float* __restrict__ b3, float* __restrict__ out)
{
    int b = blockIdx.x;
    int t = threadIdx.x;
    __shared__ float inL[HD];
    for (int c = t; c < HD; c += 128) inL[c] = h2[(size_t)b*HD + c];
    __syncthreads();
    float a0 = b3[t], a1 = 0.f, a2 = 0.f, a3 = 0.f;
    #pragma unroll 4
    for (int e = 0; e < HD; e += 4) {
        a0 += inL[e]   * W3[(size_t)e*TD + t];
        a1 += inL[e+1] * W3[(size_t)(e+1)*TD + t];
        a2 += inL[e+2] * W3[(size_t)(e+2)*TD + t];
        a3 += inL[e+3] * W3[(size_t)(e+3)*TD + t];
    }
    out[(size_t)b*TD + t] = (a0 + a1) + (a2 + a3);
}

extern "C" void kernel_launch(void* const* d_in, const int* in_sizes, int n_in,
                              void* d_out, int out_size, void* d_ws, size_t ws_size,
                              hipStream_t stream)
{
    const float* words = (const float*)d_in[0];
    const float* W_att = (const float*)d_in[1];
    const float* b_att = (const float*)d_in[2];
    const float* v     = (const float*)d_in[3];
    const float* W1    = (const float*)d_in[4];
    const float* b1    = (const float*)d_in[5];
    const float* W2    = (const float*)d_in[6];
    const float* b2    = (const float*)d_in[7];
    const float* W3    = (const float*)d_in[8];
    const float* b3    = (const float*)d_in[9];
    (void)in_sizes; (void)n_in; (void)out_size; (void)ws_size;

    float* ws   = (float*)d_ws;
    float* mask = ws + OFF_MASK;
    float* ctxp = ws + OFF_CTXP;
    float* lenp = ws + OFF_LENP;
    float* cb   = ws + OFF_CB;
    float* sc   = ws + OFF_SC;
    float* smax = ws + OFF_SMAX;
    float* sden = ws + OFF_SDEN;
    float* repp = ws + OFF_REPP;
    float* h1   = ws + OFF_H1;
    float* h2   = ws + OFF_H2;
    float* scp  = ws + OFF_SCP;
    unsigned short* Wpk = (unsigned short*)(ws + OFF_WPK);
    float* out  = (float*)d_out;

    hipLaunchKernelGGL(k0_pack,      dim3(1024), dim3(256), 0, stream, W_att, Wpk);
    hipLaunchKernelGGL(k1_maskcol,   dim3(B*8),  dim3(256), 0, stream, words, mask, ctxp, lenp);
    hipLaunchKernelGGL(k2_cb,        dim3(B*2),  dim3(256), 0, stream, W_att, b_att, ctxp, lenp, cb);
    hipLaunchKernelGGL(k3_scores,    dim3(2048), dim3(512), 0, stream, words, Wpk, cb, v, scp);
    hipLaunchKernelGGL(k4a_softstats,dim3(B),    dim3(256), 0, stream, scp, mask, sc, smax, sden);
    hipLaunchKernelGGL(k4b_rep,      dim3(B*8),  dim3(256), 0, stream, words, sc, smax, sden, repp);
    hipLaunchKernelGGL(k5a_l1,       dim3(B*2),  dim3(256), 0, stream, repp, W1, b1, h1);
    hipLaunchKernelGGL(k5b_l2,       dim3(B*2),  dim3(256), 0, stream, h1, W2, b2, h2);
    hipLaunchKernelGGL(k5c_l3,       dim3(B),    dim3(128), 0, stream, h2, W3, b3, out);
}